// Round 6
// baseline (88.768 us; speedup 1.0000x reference)
//
#include <hip/hip_runtime.h>
#include <cstddef>

#define Hn 1024
#define Vn 32000
#define Sn 4096

__device__ __forceinline__ float wave_reduce_sum(float v) {
#pragma unroll
    for (int o = 32; o > 0; o >>= 1) v += __shfl_down(v, o, 64);
    return v;
}
__device__ __forceinline__ float wave_reduce_max(float v) {
#pragma unroll
    for (int o = 32; o > 0; o >>= 1) v = fmaxf(v, __shfl_down(v, o, 64));
    return v;
}

// ws layout (floats):
// [0,1024)      h            (c2 = [h, context] contiguous)
// [1024,2048)   context      (atomicAdd target, zeroed by k_gru block 0)
// [2048,3072)   v = attn_w^T h
// [3072,7168)   scores

// ---------------- K1: GRU cell -> h (1024 blocks, block per output) ----------------
__global__ __launch_bounds__(256) void k_gru(const int* __restrict__ word,
                                             const float* __restrict__ emb,
                                             const float* __restrict__ h0,
                                             const float* __restrict__ w_ih,
                                             const float* __restrict__ w_hh,
                                             const float* __restrict__ b_ih,
                                             const float* __restrict__ b_hh,
                                             float* __restrict__ ws_h,
                                             float* __restrict__ ws_ctx,
                                             float* __restrict__ out_h)
{
    const int k = blockIdx.x;
    const int t = threadIdx.x;

    if (k == 0) {               // zero the context atomic target for this call
#pragma unroll
        for (int i = 0; i < 4; ++i) ws_ctx[t + i * 256] = 0.f;
    }

    const float* x = emb + (size_t)word[0] * Hn;
    const float4 xv = ((const float4*)x)[t];
    const float4 hv = ((const float4*)h0)[t];

    float acc[6];
    const float* rows[6] = {
        w_ih + (size_t)k * Hn, w_ih + (size_t)(k + Hn) * Hn, w_ih + (size_t)(k + 2 * Hn) * Hn,
        w_hh + (size_t)k * Hn, w_hh + (size_t)(k + Hn) * Hn, w_hh + (size_t)(k + 2 * Hn) * Hn
    };
#pragma unroll
    for (int g = 0; g < 6; ++g) {
        const float4 w = ((const float4*)rows[g])[t];
        const float4 vv = (g < 3) ? xv : hv;
        acc[g] = w.x * vv.x + w.y * vv.y + w.z * vv.z + w.w * vv.w;
    }

    __shared__ float red[6][4];
    const int wv = t >> 6, lane = t & 63;
#pragma unroll
    for (int g = 0; g < 6; ++g) {
        const float s = wave_reduce_sum(acc[g]);
        if (lane == 0) red[g][wv] = s;
    }
    __syncthreads();
    if (t == 0) {
        float g0 = red[0][0] + red[0][1] + red[0][2] + red[0][3] + b_ih[k];
        float g1 = red[1][0] + red[1][1] + red[1][2] + red[1][3] + b_ih[k + Hn];
        float g2 = red[2][0] + red[2][1] + red[2][2] + red[2][3] + b_ih[k + 2 * Hn];
        float g3 = red[3][0] + red[3][1] + red[3][2] + red[3][3] + b_hh[k];
        float g4 = red[4][0] + red[4][1] + red[4][2] + red[4][3] + b_hh[k + Hn];
        float g5 = red[5][0] + red[5][1] + red[5][2] + red[5][3] + b_hh[k + 2 * Hn];
        float r = 1.f / (1.f + expf(-(g0 + g3)));
        float z = 1.f / (1.f + expf(-(g1 + g4)));
        float n = tanhf(g2 + r * g5);
        float hk = (1.f - z) * n + z * h0[k];
        ws_h[k]  = hk;
        out_h[k] = hk;
    }
}

// ---------------- K2: v = attn_w^T h (64 blocks, 16-col strip) ----------------
__global__ __launch_bounds__(256) void k_attnv(const float* __restrict__ attn_w,
                                               const float* __restrict__ ws_h,
                                               float* __restrict__ v)
{
    const int t = threadIdx.x;
    const int tj = t >> 4;                 // 0..15 row-group
    const int tk = t & 15;                 // 0..15 column within block
    const int k = blockIdx.x * 16 + tk;
    float acc = 0.f;
    for (int j = tj; j < Hn; j += 16)
        acc += attn_w[(size_t)j * Hn + k] * ws_h[j];
    __shared__ float p[16][17];
    p[tj][tk] = acc;
    __syncthreads();
    if (t < 16) {
        float s = 0.f;
#pragma unroll
        for (int j = 0; j < 16; ++j) s += p[j][t];
        v[blockIdx.x * 16 + t] = s;
    }
}

// ---------------- K3: scores[s] = enc[s] . v ----------------
__global__ __launch_bounds__(256) void k_scores(const float* __restrict__ enc,
                                                const float* __restrict__ ws_v,
                                                float* __restrict__ scores)
{
    __shared__ float v[Hn];
    const int t = threadIdx.x;
    ((float4*)v)[t] = ((const float4*)ws_v)[t];
    __syncthreads();
    const int wv = t >> 6, lane = t & 63;
    const int s = blockIdx.x * 4 + wv;
    const float* row = enc + (size_t)s * Hn;
    float acc = 0.f;
#pragma unroll
    for (int k = 0; k < 4; ++k) {
        const int idx = k * 256 + lane * 4;
        const float4 e = *(const float4*)(row + idx);
        acc += e.x * v[idx] + e.y * v[idx + 1] + e.z * v[idx + 2] + e.w * v[idx + 3];
    }
    acc = wave_reduce_sum(acc);
    if (lane == 0) scores[s] = acc;
}

// -------- K4: softmax (per-block recompute) + context via atomicAdd --------
__global__ __launch_bounds__(256) void k_ctx(const float* __restrict__ enc,
                                             const float* __restrict__ scores,
                                             float* __restrict__ ctx,
                                             float* __restrict__ out_attn)
{
    const int t = threadIdx.x, bid = blockIdx.x;
    const int wv = t >> 6, lane = t & 63;
    __shared__ float red[4];
    __shared__ float aw[64];

    float4 sc[4];
#pragma unroll
    for (int i = 0; i < 4; ++i) sc[i] = ((const float4*)scores)[i * 256 + t];
    float m = -1e30f;
#pragma unroll
    for (int i = 0; i < 4; ++i)
        m = fmaxf(m, fmaxf(fmaxf(sc[i].x, sc[i].y), fmaxf(sc[i].z, sc[i].w)));
    m = wave_reduce_max(m);
    if (lane == 0) red[wv] = m;
    __syncthreads();
    const float mx = fmaxf(fmaxf(red[0], red[1]), fmaxf(red[2], red[3]));
    float ps = 0.f;
#pragma unroll
    for (int i = 0; i < 4; ++i)
        ps += expf(sc[i].x - mx) + expf(sc[i].y - mx) + expf(sc[i].z - mx) + expf(sc[i].w - mx);
    ps = wave_reduce_sum(ps);
    __syncthreads();
    if (lane == 0) red[wv] = ps;
    __syncthreads();
    const float inv = 1.f / (red[0] + red[1] + red[2] + red[3]);

    const int s0 = bid * 64;
    if (t < 64) {
        const float a = expf(scores[s0 + t] - mx) * inv;
        aw[t] = a;
        out_attn[s0 + t] = a;
    }
    __syncthreads();

    float acc0 = 0.f, acc1 = 0.f, acc2 = 0.f, acc3 = 0.f;
    const float* base = enc + (size_t)s0 * Hn;
#pragma unroll 4
    for (int s = 0; s < 64; ++s) {
        const float a = aw[s];
        const float* row = base + (size_t)s * Hn;
        acc0 += a * row[t];
        acc1 += a * row[t + 256];
        acc2 += a * row[t + 512];
        acc3 += a * row[t + 768];
    }
    atomicAdd(&ctx[t],       acc0);
    atomicAdd(&ctx[t + 256], acc1);
    atomicAdd(&ctx[t + 512], acc2);
    atomicAdd(&ctx[t + 768], acc3);
}

// ------- K5: out = out_w.[h,ctx] + out_b — 16 rows/block, 4 rows/wave -------
__global__ __launch_bounds__(256) void k_out(const float* __restrict__ out_w,
                                             const float* __restrict__ out_b,
                                             const float* __restrict__ c2,
                                             float* __restrict__ out)
{
    __shared__ float c[2 * Hn];
    const int t = threadIdx.x;
    ((float4*)c)[t]       = ((const float4*)c2)[t];
    ((float4*)c)[t + 256] = ((const float4*)c2)[t + 256];
    __syncthreads();
    const int wv = t >> 6, lane = t & 63;
    const int row0 = blockIdx.x * 16 + wv * 4;   // 4 consecutive rows per wave
    const float* w0 = out_w + (size_t)row0 * (2 * Hn);
    const float* w1 = w0 + 2 * Hn;
    const float* w2 = w1 + 2 * Hn;
    const float* w3 = w2 + 2 * Hn;

    float a0 = 0.f, a1 = 0.f, a2 = 0.f, a3 = 0.f;
#pragma unroll 4
    for (int k = 0; k < 8; ++k) {
        const int idx = k * 256 + lane * 4;
        const float4 r0 = *(const float4*)(w0 + idx);
        const float4 r1 = *(const float4*)(w1 + idx);
        const float4 r2 = *(const float4*)(w2 + idx);
        const float4 r3 = *(const float4*)(w3 + idx);
        const float c0 = c[idx], c1v = c[idx + 1], c2v = c[idx + 2], c3v = c[idx + 3];
        a0 += r0.x * c0 + r0.y * c1v + r0.z * c2v + r0.w * c3v;
        a1 += r1.x * c0 + r1.y * c1v + r1.z * c2v + r1.w * c3v;
        a2 += r2.x * c0 + r2.y * c1v + r2.z * c2v + r2.w * c3v;
        a3 += r3.x * c0 + r3.y * c1v + r3.z * c2v + r3.w * c3v;
    }
    a0 = wave_reduce_sum(a0);
    a1 = wave_reduce_sum(a1);
    a2 = wave_reduce_sum(a2);
    a3 = wave_reduce_sum(a3);
    if (lane == 0) {
        out[row0]     = a0 + out_b[row0];
        out[row0 + 1] = a1 + out_b[row0 + 1];
        out[row0 + 2] = a2 + out_b[row0 + 2];
        out[row0 + 3] = a3 + out_b[row0 + 3];
    }
}

extern "C" void kernel_launch(void* const* d_in, const int* in_sizes, int n_in,
                              void* d_out, int out_size, void* d_ws, size_t ws_size,
                              hipStream_t stream) {
    const int*   word   = (const int*)d_in[0];
    const float* h_last = (const float*)d_in[1];
    const float* enc    = (const float*)d_in[2];
    const float* emb    = (const float*)d_in[3];
    const float* w_ih   = (const float*)d_in[4];
    const float* w_hh   = (const float*)d_in[5];
    const float* b_ih   = (const float*)d_in[6];
    const float* b_hh   = (const float*)d_in[7];
    const float* attn_w = (const float*)d_in[8];
    /* d_in[9] attn_b: unused — uniform shift, softmax-invariant */
    const float* out_w  = (const float*)d_in[10];
    const float* out_b  = (const float*)d_in[11];
    float* out = (float*)d_out;
    float* ws  = (float*)d_ws;

    float* ws_h      = ws;          // 1024
    float* ws_ctx    = ws + 1024;   // 1024 (c2 = [h, ctx] contiguous at ws)
    float* ws_v      = ws + 2048;   // 1024
    float* ws_scores = ws + 3072;   // 4096

    k_gru<<<Hn, 256, 0, stream>>>(word, emb, h_last, w_ih, w_hh, b_ih, b_hh, ws_h, ws_ctx, out + Vn);
    k_attnv<<<Hn / 16, 256, 0, stream>>>(attn_w, ws_h, ws_v);
    k_scores<<<Sn / 4, 256, 0, stream>>>(enc, ws_v, ws_scores);
    k_ctx<<<Sn / 64, 256, 0, stream>>>(enc, ws_scores, ws_ctx, out + Vn + Hn);
    k_out<<<Vn / 16, 256, 0, stream>>>(out_w, out_b, ws, out);
}